// Round 4
// baseline (1099.073 us; speedup 1.0000x reference)
//
#include <hip/hip_runtime.h>
#include <hip/hip_bf16.h>

#define TB 256

constexpr int B_ = 8, N_ = 2048, C_ = 64, H_ = 2;
constexpr float SCALE = 0.125f;      // C**-0.5
constexpr float NEGV = -1e10f;
constexpr float LN_EPS = 1e-5f;
constexpr size_t SCH = (size_t)B_ * N_ * C_;   // 1048576 elements per [B,N,C] buffer

__device__ __forceinline__ float wave_reduce_sum(float v) {
#pragma unroll
  for (int off = 32; off >= 1; off >>= 1) v += __shfl_xor(v, off, 64);
  return v;
}
__device__ __forceinline__ float wave_reduce_max(float v) {
#pragma unroll
  for (int off = 32; off >= 1; off >>= 1) v = fmaxf(v, __shfl_xor(v, off, 64));
  return v;
}

// ---------------- projections: qd,kd,vd,qs,ks,vs = x @ W (+bias) ----------------
__global__ __launch_bounds__(TB) void proj_kernel(
    const float* __restrict__ x,
    const float* __restrict__ wqd, const float* __restrict__ wkd,
    const float* __restrict__ wvd, const float* __restrict__ bvd,
    const float* __restrict__ wqs, const float* __restrict__ wks,
    const float* __restrict__ wvs, const float* __restrict__ bvs,
    float* __restrict__ ws) {
  const int t = threadIdx.x;
  const int row = blockIdx.x * 16 + (t >> 4);  // 16 rows/block
  const int cg = t & 15;                        // 4-column group
  float xr[64];
  const float4* xp = reinterpret_cast<const float4*>(x + (size_t)row * 64);
#pragma unroll
  for (int i = 0; i < 16; ++i) {
    float4 v = xp[i];
    xr[4 * i] = v.x; xr[4 * i + 1] = v.y; xr[4 * i + 2] = v.z; xr[4 * i + 3] = v.w;
  }
  const float* W[6] = {wqd, wkd, wvd, wqs, wks, wvs};
#pragma unroll
  for (int m = 0; m < 6; ++m) {
    float4 acc = make_float4(0.f, 0.f, 0.f, 0.f);
    if (m == 2) acc = reinterpret_cast<const float4*>(bvd)[cg];
    if (m == 5) acc = reinterpret_cast<const float4*>(bvs)[cg];
    const float4* wp = reinterpret_cast<const float4*>(W[m]) + cg;
#pragma unroll
    for (int c = 0; c < 64; ++c) {
      float4 w4 = wp[(size_t)c * 16];
      float s = xr[c];
      acc.x += s * w4.x; acc.y += s * w4.y; acc.z += s * w4.z; acc.w += s * w4.w;
    }
    reinterpret_cast<float4*>(ws + (size_t)m * SCH + (size_t)row * 64)[cg] = acc;
  }
}

// ---------------- edge bitmask ----------------
__global__ void zero_mask_kernel(unsigned int* __restrict__ mb) {
  mb[(size_t)blockIdx.x * TB + threadIdx.x] = 0u;
}
__global__ void scatter_kernel(const int* __restrict__ edge, int E,
                               unsigned int* __restrict__ mb) {
  int e = blockIdx.x * TB + threadIdx.x;
  if (e < E) {
    int r = edge[e];
    int c = edge[E + e];
    atomicOr(&mb[r * (N_ / 32) + (c >> 5)], 1u << (c & 31));
  }
}

// ---------------- DMHSA: dynamic mean-masked attention ----------------
__global__ __launch_bounds__(TB) void dmhsa_kernel(
    const float* __restrict__ qd, const float* __restrict__ kd,
    const float* __restrict__ vd, float* __restrict__ od,
    float* __restrict__ attn_out) {
  __shared__ float S[8][N_];
  __shared__ float qt[8][32];
  __shared__ float rmean[8], rmax[8], rinv[8];
  __shared__ float scr[4][8][32];

  const int t = threadIdx.x;
  const int bh = blockIdx.y;
  const int b = bh >> 1, h = bh & 1;
  const int row0 = blockIdx.x * 8;
  const size_t bbase = (size_t)b * N_ * 64 + (size_t)h * 32;

  if (t < 64) {
    int r = t >> 3, c4 = t & 7;
    *reinterpret_cast<float4*>(&qt[r][c4 * 4]) =
        *reinterpret_cast<const float4*>(qd + bbase + (size_t)(row0 + r) * 64 + c4 * 4);
  }
  __syncthreads();

  // phase 1: S = q @ k^T * scale (8 rows x 8 cols per thread register tile)
  {
    float acc[8][8];
#pragma unroll
    for (int r = 0; r < 8; ++r)
#pragma unroll
      for (int jj = 0; jj < 8; ++jj) acc[r][jj] = 0.f;
    for (int c4 = 0; c4 < 8; ++c4) {
      float4 q4[8];
#pragma unroll
      for (int r = 0; r < 8; ++r) q4[r] = *reinterpret_cast<const float4*>(&qt[r][c4 * 4]);
#pragma unroll
      for (int jj = 0; jj < 8; ++jj) {
        int j = t + jj * TB;
        float4 k4 = *reinterpret_cast<const float4*>(kd + bbase + (size_t)j * 64 + c4 * 4);
#pragma unroll
        for (int r = 0; r < 8; ++r)
          acc[r][jj] += q4[r].x * k4.x + q4[r].y * k4.y + q4[r].z * k4.z + q4[r].w * k4.w;
      }
    }
#pragma unroll
    for (int r = 0; r < 8; ++r)
#pragma unroll
      for (int jj = 0; jj < 8; ++jj) S[r][t + jj * TB] = acc[r][jj] * SCALE;
  }
  __syncthreads();

  const int wv = t >> 6, lane = t & 63;
  // phase 2: row mean & max (wave per 2 rows)
#pragma unroll
  for (int rr = 0; rr < 2; ++rr) {
    int r = wv * 2 + rr;
    float sm = 0.f, mx = -1e30f;
#pragma unroll
    for (int i = 0; i < 8; ++i) {
      float4 v = *reinterpret_cast<const float4*>(&S[r][(i * 64 + lane) * 4]);
      sm += (v.x + v.y) + (v.z + v.w);
      mx = fmaxf(mx, fmaxf(fmaxf(v.x, v.y), fmaxf(v.z, v.w)));
    }
    sm = wave_reduce_sum(sm);
    mx = wave_reduce_max(mx);
    if (lane == 0) { rmean[r] = sm * (1.f / N_); rmax[r] = mx; }
  }
  __syncthreads();
  // phase 3a: masked exp + denom (row max >= row mean so max is always unmasked)
#pragma unroll
  for (int rr = 0; rr < 2; ++rr) {
    int r = wv * 2 + rr;
    float mean = rmean[r], mx = rmax[r];
    float sm = 0.f;
#pragma unroll
    for (int i = 0; i < 8; ++i) {
      int j0 = (i * 64 + lane) * 4;
      float4 v = *reinterpret_cast<float4*>(&S[r][j0]);
      v.x = (v.x >= mean) ? __expf(v.x - mx) : 0.f;
      v.y = (v.y >= mean) ? __expf(v.y - mx) : 0.f;
      v.z = (v.z >= mean) ? __expf(v.z - mx) : 0.f;
      v.w = (v.w >= mean) ? __expf(v.w - mx) : 0.f;
      *reinterpret_cast<float4*>(&S[r][j0]) = v;
      sm += (v.x + v.y) + (v.z + v.w);
    }
    sm = wave_reduce_sum(sm);
    if (lane == 0) rinv[r] = 1.f / sm;
  }
  __syncthreads();
  // phase 3b: write normalized attention rows (output 1)
  {
    float* aout = attn_out + ((size_t)bh * N_ + row0) * N_;
#pragma unroll
    for (int i = 0; i < 16; ++i) {
      int q4i = t + i * TB;
      int r = q4i >> 9;
      int j = (q4i & 511) * 4;
      float4 v = *reinterpret_cast<const float4*>(&S[r][j]);
      float inv = rinv[r];
      v.x *= inv; v.y *= inv; v.z *= inv; v.w *= inv;
      *reinterpret_cast<float4*>(aout + (size_t)r * N_ + j) = v;
    }
  }
  // phase 4: O = (e @ V) * rinv ; per-thread 4-row x 8-dim tile, 32 j-groups
  {
    const int jg = t >> 3, sub = t & 7;
    const int rh = sub >> 2, dh = sub & 3;
    float pa[4][8];
#pragma unroll
    for (int rr = 0; rr < 4; ++rr)
#pragma unroll
      for (int dd = 0; dd < 8; ++dd) pa[rr][dd] = 0.f;
    const float* vb = vd + bbase + dh * 8;
    for (int i = 0; i < 64; ++i) {
      int j = jg + i * 32;
      float4 v0 = *reinterpret_cast<const float4*>(vb + (size_t)j * 64);
      float4 v1 = *reinterpret_cast<const float4*>(vb + (size_t)j * 64 + 4);
#pragma unroll
      for (int rr = 0; rr < 4; ++rr) {
        float a = S[rh * 4 + rr][j];
        pa[rr][0] += a * v0.x; pa[rr][1] += a * v0.y;
        pa[rr][2] += a * v0.z; pa[rr][3] += a * v0.w;
        pa[rr][4] += a * v1.x; pa[rr][5] += a * v1.y;
        pa[rr][6] += a * v1.z; pa[rr][7] += a * v1.w;
      }
    }
#pragma unroll
    for (int off = 8; off <= 32; off <<= 1)
#pragma unroll
      for (int rr = 0; rr < 4; ++rr)
#pragma unroll
        for (int dd = 0; dd < 8; ++dd)
          pa[rr][dd] += __shfl_xor(pa[rr][dd], off, 64);
    if (lane < 8) {
#pragma unroll
      for (int rr = 0; rr < 4; ++rr)
#pragma unroll
        for (int dd = 0; dd < 8; ++dd)
          scr[wv][lane][rr * 8 + dd] = pa[rr][dd];
    }
    __syncthreads();
    {
      int r = t >> 5, d = t & 31;
      int sub2 = (r >> 2) * 4 + (d >> 3);
      int idx = (r & 3) * 8 + (d & 7);
      float o = scr[0][sub2][idx] + scr[1][sub2][idx] + scr[2][sub2][idx] + scr[3][sub2][idx];
      od[(size_t)b * N_ * 64 + (size_t)(row0 + r) * 64 + h * 32 + d] = o * rinv[r];
    }
  }
}

// ---------------- SSA: static edge-masked single-head attention ----------------
__global__ __launch_bounds__(TB) void ssa_kernel(
    const float* __restrict__ qs, const float* __restrict__ ks,
    const float* __restrict__ vs, const unsigned int* __restrict__ mb,
    float* __restrict__ osb) {
  __shared__ float S[8][N_];
  __shared__ float qt[8][64];
  __shared__ float rmax[8], rinv[8];
  __shared__ float scr[4][8][64];

  const int t = threadIdx.x;
  const int b = blockIdx.y;
  const int row0 = blockIdx.x * 8;
  const size_t bbase = (size_t)b * N_ * 64;

  if (t < 128) {
    int r = t >> 4, c4 = t & 15;
    *reinterpret_cast<float4*>(&qt[r][c4 * 4]) =
        *reinterpret_cast<const float4*>(qs + bbase + (size_t)(row0 + r) * 64 + c4 * 4);
  }
  __syncthreads();

  // phase 1: S = where(edge, qs@ks^T*scale, NEG)
  {
    float acc[8][8];
#pragma unroll
    for (int r = 0; r < 8; ++r)
#pragma unroll
      for (int jj = 0; jj < 8; ++jj) acc[r][jj] = 0.f;
    for (int c4 = 0; c4 < 16; ++c4) {
      float4 q4[8];
#pragma unroll
      for (int r = 0; r < 8; ++r) q4[r] = *reinterpret_cast<const float4*>(&qt[r][c4 * 4]);
#pragma unroll
      for (int jj = 0; jj < 8; ++jj) {
        int j = t + jj * TB;
        float4 k4 = *reinterpret_cast<const float4*>(ks + bbase + (size_t)j * 64 + c4 * 4);
#pragma unroll
        for (int r = 0; r < 8; ++r)
          acc[r][jj] += q4[r].x * k4.x + q4[r].y * k4.y + q4[r].z * k4.z + q4[r].w * k4.w;
      }
    }
#pragma unroll
    for (int jj = 0; jj < 8; ++jj) {
      int j = t + jj * TB;
      int wcol = j >> 5;
      unsigned bit = 1u << (j & 31);
#pragma unroll
      for (int r = 0; r < 8; ++r) {
        unsigned w = mb[(row0 + r) * (N_ / 32) + wcol];
        S[r][j] = (w & bit) ? acc[r][jj] * SCALE : NEGV;
      }
    }
  }
  __syncthreads();

  const int wv = t >> 6, lane = t & 63;
  // phase 2: row max
#pragma unroll
  for (int rr = 0; rr < 2; ++rr) {
    int r = wv * 2 + rr;
    float mx = -1e30f;
#pragma unroll
    for (int i = 0; i < 8; ++i) {
      float4 v = *reinterpret_cast<const float4*>(&S[r][(i * 64 + lane) * 4]);
      mx = fmaxf(mx, fmaxf(fmaxf(v.x, v.y), fmaxf(v.z, v.w)));
    }
    mx = wave_reduce_max(mx);
    if (lane == 0) rmax[r] = mx;
  }
  __syncthreads();
  // phase 3: exp + denom (all-masked rows -> uniform, matches reference)
#pragma unroll
  for (int rr = 0; rr < 2; ++rr) {
    int r = wv * 2 + rr;
    float mx = rmax[r];
    float sm = 0.f;
#pragma unroll
    for (int i = 0; i < 8; ++i) {
      int j0 = (i * 64 + lane) * 4;
      float4 v = *reinterpret_cast<float4*>(&S[r][j0]);
      v.x = __expf(v.x - mx);
      v.y = __expf(v.y - mx);
      v.z = __expf(v.z - mx);
      v.w = __expf(v.w - mx);
      *reinterpret_cast<float4*>(&S[r][j0]) = v;
      sm += (v.x + v.y) + (v.z + v.w);
    }
    sm = wave_reduce_sum(sm);
    if (lane == 0) rinv[r] = 1.f / sm;
  }
  __syncthreads();
  // phase 4: O = (e @ V) * rinv ; per-thread 4-row x 16-dim tile, 32 j-groups
  {
    const int jg = t >> 3, sub = t & 7;
    const int rh = sub >> 2, dh = sub & 3;
    float pa[4][16];
#pragma unroll
    for (int rr = 0; rr < 4; ++rr)
#pragma unroll
      for (int dd = 0; dd < 16; ++dd) pa[rr][dd] = 0.f;
    const float* vb = vs + bbase + dh * 16;
    for (int i = 0; i < 64; ++i) {
      int j = jg + i * 32;
      float4 v0 = *reinterpret_cast<const float4*>(vb + (size_t)j * 64);
      float4 v1 = *reinterpret_cast<const float4*>(vb + (size_t)j * 64 + 4);
      float4 v2 = *reinterpret_cast<const float4*>(vb + (size_t)j * 64 + 8);
      float4 v3 = *reinterpret_cast<const float4*>(vb + (size_t)j * 64 + 12);
#pragma unroll
      for (int rr = 0; rr < 4; ++rr) {
        float a = S[rh * 4 + rr][j];
        pa[rr][0] += a * v0.x;  pa[rr][1] += a * v0.y;
        pa[rr][2] += a * v0.z;  pa[rr][3] += a * v0.w;
        pa[rr][4] += a * v1.x;  pa[rr][5] += a * v1.y;
        pa[rr][6] += a * v1.z;  pa[rr][7] += a * v1.w;
        pa[rr][8] += a * v2.x;  pa[rr][9] += a * v2.y;
        pa[rr][10] += a * v2.z; pa[rr][11] += a * v2.w;
        pa[rr][12] += a * v3.x; pa[rr][13] += a * v3.y;
        pa[rr][14] += a * v3.z; pa[rr][15] += a * v3.w;
      }
    }
#pragma unroll
    for (int off = 8; off <= 32; off <<= 1)
#pragma unroll
      for (int rr = 0; rr < 4; ++rr)
#pragma unroll
        for (int dd = 0; dd < 16; ++dd)
          pa[rr][dd] += __shfl_xor(pa[rr][dd], off, 64);
    if (lane < 8) {
#pragma unroll
      for (int rr = 0; rr < 4; ++rr)
#pragma unroll
        for (int dd = 0; dd < 16; ++dd)
          scr[wv][lane][rr * 16 + dd] = pa[rr][dd];
    }
    __syncthreads();
#pragma unroll
    for (int u = 0; u < 2; ++u) {
      int idx = t + u * TB;
      int r = idx >> 6, d = idx & 63;
      int sub2 = (r >> 2) * 4 + (d >> 4);
      int i2 = (r & 3) * 16 + (d & 15);
      float o = scr[0][sub2][i2] + scr[1][sub2][i2] + scr[2][sub2][i2] + scr[3][sub2][i2];
      osb[bbase + (size_t)(row0 + r) * 64 + d] = o * rinv[r];
    }
  }
}

// ---------------- residual + LN1 + MLP + LN2 ----------------
__global__ __launch_bounds__(TB) void epi_kernel(
    const float* __restrict__ x, const float* __restrict__ od,
    const float* __restrict__ osb,
    const float* __restrict__ g1, const float* __restrict__ bb1,
    const float* __restrict__ g2, const float* __restrict__ bb2,
    const float* __restrict__ w1, const float* __restrict__ bm1,
    const float* __restrict__ w2, const float* __restrict__ bm2,
    float* __restrict__ out) {
  __shared__ float hl[4][64];
  __shared__ float tl[4][128];
  const int t = threadIdx.x, wv = t >> 6, c = t & 63;
  const size_t row = (size_t)blockIdx.x * 4 + wv;
  const size_t base = row * 64 + c;
  float res = od[base] + osb[base] + x[base];
  float mean = wave_reduce_sum(res) * (1.f / 64.f);
  float dlt = res - mean;
  float var = wave_reduce_sum(dlt * dlt) * (1.f / 64.f);
  float hval = dlt * rsqrtf(var + LN_EPS) * g1[c] + bb1[c];
  hl[wv][c] = hval;
  __syncthreads();
  float t0 = bm1[2 * c], t1 = bm1[2 * c + 1];
#pragma unroll 16
  for (int cc = 0; cc < 64; ++cc) {
    float hv = hl[wv][cc];
    float2 wv2 = *reinterpret_cast<const float2*>(w1 + (size_t)cc * 128 + 2 * c);
    t0 += hv * wv2.x; t1 += hv * wv2.y;
  }
  *reinterpret_cast<float2*>(&tl[wv][2 * c]) = make_float2(t0, t1);
  __syncthreads();
  float m = bm2[c];
#pragma unroll 8
  for (int j4 = 0; j4 < 32; ++j4) {
    float4 t4 = *reinterpret_cast<const float4*>(&tl[wv][j4 * 4]);
    m += t4.x * w2[(size_t)(j4 * 4 + 0) * 64 + c];
    m += t4.y * w2[(size_t)(j4 * 4 + 1) * 64 + c];
    m += t4.z * w2[(size_t)(j4 * 4 + 2) * 64 + c];
    m += t4.w * w2[(size_t)(j4 * 4 + 3) * 64 + c];
  }
  float y = m + res;
  float mean2 = wave_reduce_sum(y) * (1.f / 64.f);
  float d2 = y - mean2;
  float var2 = wave_reduce_sum(d2 * d2) * (1.f / 64.f);
  out[base] = d2 * rsqrtf(var2 + LN_EPS) * g2[c] + bb2[c];
}

extern "C" void kernel_launch(void* const* d_in, const int* in_sizes, int n_in,
                              void* d_out, int out_size, void* d_ws, size_t ws_size,
                              hipStream_t stream) {
  const float* x   = (const float*)d_in[0];
  const int*   edge = (const int*)d_in[1];
  // d_in[2] = num_heads (known: 2)
  const float* wqd = (const float*)d_in[3];
  const float* wkd = (const float*)d_in[4];
  const float* wvd = (const float*)d_in[5];
  const float* bvd = (const float*)d_in[6];
  const float* wqs = (const float*)d_in[7];
  const float* wks = (const float*)d_in[8];
  const float* wvs = (const float*)d_in[9];
  const float* bvs = (const float*)d_in[10];
  const float* g1  = (const float*)d_in[11];
  const float* b1g = (const float*)d_in[12];
  const float* g2  = (const float*)d_in[13];
  const float* b2g = (const float*)d_in[14];
  const float* w1  = (const float*)d_in[15];
  const float* bm1 = (const float*)d_in[16];
  const float* w2  = (const float*)d_in[17];
  const float* bm2 = (const float*)d_in[18];
  const int E = in_sizes[1] / 2;

  float* out  = (float*)d_out;
  float* attn = out + SCH;                  // [B,H,N,N] fp32
  float* ws   = (float*)d_ws;
  float* qd  = ws + 0 * SCH;
  float* kd  = ws + 1 * SCH;
  float* vd  = ws + 2 * SCH;
  float* qsb = ws + 3 * SCH;
  float* ksb = ws + 4 * SCH;
  float* vsb = ws + 5 * SCH;
  float* od  = ws + 6 * SCH;
  float* osb = ws + 7 * SCH;
  unsigned int* mb = (unsigned int*)(ws + 8 * SCH);   // N*N bits = 512KB

  proj_kernel<<<(B_ * N_) / 16, TB, 0, stream>>>(x, wqd, wkd, wvd, bvd, wqs, wks, wvs, bvs, ws);
  zero_mask_kernel<<<(N_ * N_ / 32) / TB, TB, 0, stream>>>(mb);
  scatter_kernel<<<(E + TB - 1) / TB, TB, 0, stream>>>(edge, E, mb);
  dmhsa_kernel<<<dim3(N_ / 8, B_ * H_), TB, 0, stream>>>(qd, kd, vd, od, attn);
  ssa_kernel<<<dim3(N_ / 8, B_), TB, 0, stream>>>(qsb, ksb, vsb, mb, osb);
  epi_kernel<<<(B_ * N_) / 4, TB, 0, stream>>>(x, od, osb, g1, b1g, g2, b2g, w1, bm1, w2, bm2, out);
}

// Round 9
// 558.436 us; speedup vs baseline: 1.9681x; 1.9681x over previous
//
#include <hip/hip_runtime.h>
#include <hip/hip_bf16.h>

#define TB 256

constexpr int B_ = 8, N_ = 2048, H_ = 2;
constexpr float SCALE = 0.125f;      // C**-0.5, exact power of two
constexpr float NEGV = -1e10f;
constexpr float LN_EPS = 1e-5f;
constexpr size_t SCH = (size_t)B_ * N_ * 64;   // 1M elements per [B,N,C]

typedef __attribute__((ext_vector_type(8))) short bf16x8;
typedef __attribute__((ext_vector_type(4))) float f32x4;
typedef __attribute__((ext_vector_type(8))) unsigned short us8;
typedef __attribute__((ext_vector_type(4))) unsigned short us4;

#define MFMA16(A, B, C) __builtin_amdgcn_mfma_f32_16x16x32_bf16((A), (B), (C), 0, 0, 0)

__device__ __forceinline__ unsigned short f2b(float f) {
  __hip_bfloat16 h = __float2bfloat16(f);
  return *reinterpret_cast<unsigned short*>(&h);
}
__device__ __forceinline__ float b2f(unsigned short u) {
  union { unsigned int i; float f; } v; v.i = ((unsigned int)u) << 16; return v.f;
}
// S-tile LDS swizzle: rows are 4096B, XOR row&7 into the 16B-block index (G4 fix)
__device__ __forceinline__ int swz(int off) { return off ^ (((off >> 12) & 7) << 4); }

__device__ __forceinline__ float wave_reduce_sum(float v) {
#pragma unroll
  for (int off = 32; off >= 1; off >>= 1) v += __shfl_xor(v, off, 64);
  return v;
}
__device__ __forceinline__ float wave_reduce_max(float v) {
#pragma unroll
  for (int off = 32; off >= 1; off >>= 1) v = fmaxf(v, __shfl_xor(v, off, 64));
  return v;
}

// ---------------- projections ----------------
// outputs: q16d,k16d [B*H][N][32] bf16 (q pre-scaled), vd fp32 [B][N][64] (+bias)
//          q16s,k16s [B][N][64] bf16 (q pre-scaled), vsb fp32 [B][N][64] (+bias)
__global__ __launch_bounds__(TB) void proj_kernel(
    const float* __restrict__ x,
    const float* __restrict__ wqd, const float* __restrict__ wkd,
    const float* __restrict__ wvd, const float* __restrict__ bvd,
    const float* __restrict__ wqs, const float* __restrict__ wks,
    const float* __restrict__ wvs, const float* __restrict__ bvs,
    float* __restrict__ vd, float* __restrict__ vsb,
    unsigned short* __restrict__ q16d, unsigned short* __restrict__ k16d,
    unsigned short* __restrict__ q16s, unsigned short* __restrict__ k16s) {
  const int t = threadIdx.x;
  const int row = blockIdx.x * 16 + (t >> 4);
  const int cg = t & 15;
  const int b = row >> 11, n = row & 2047;
  float xr[64];
  const float4* xp = reinterpret_cast<const float4*>(x + (size_t)row * 64);
#pragma unroll
  for (int i = 0; i < 16; ++i) {
    float4 v = xp[i];
    xr[4 * i] = v.x; xr[4 * i + 1] = v.y; xr[4 * i + 2] = v.z; xr[4 * i + 3] = v.w;
  }
  const float* W[6] = {wqd, wkd, wvd, wqs, wks, wvs};
#pragma unroll
  for (int m = 0; m < 6; ++m) {
    float4 acc = make_float4(0.f, 0.f, 0.f, 0.f);
    if (m == 2) acc = reinterpret_cast<const float4*>(bvd)[cg];
    if (m == 5) acc = reinterpret_cast<const float4*>(bvs)[cg];
    const float4* wp = reinterpret_cast<const float4*>(W[m]) + cg;
#pragma unroll
    for (int c = 0; c < 64; ++c) {
      float4 w4 = wp[(size_t)c * 16];
      float s = xr[c];
      acc.x += s * w4.x; acc.y += s * w4.y; acc.z += s * w4.z; acc.w += s * w4.w;
    }
    if (m == 2) {
      reinterpret_cast<float4*>(vd + (size_t)row * 64)[cg] = acc;
    } else if (m == 5) {
      reinterpret_cast<float4*>(vsb + (size_t)row * 64)[cg] = acc;
    } else {
      float sc = (m == 0 || m == 3) ? SCALE : 1.f;
      us4 o; o.x = f2b(acc.x * sc); o.y = f2b(acc.y * sc);
      o.z = f2b(acc.z * sc); o.w = f2b(acc.w * sc);
      if (m == 0 || m == 1) {
        unsigned short* dst = (m == 0) ? q16d : k16d;
        size_t idx = ((size_t)(b * 2 + (cg >> 3)) * 2048 + n) * 32 + (cg & 7) * 4;
        *reinterpret_cast<us4*>(dst + idx) = o;
      } else {
        unsigned short* dst = (m == 3) ? q16s : k16s;
        *reinterpret_cast<us4*>(dst + (size_t)row * 64 + cg * 4) = o;
      }
    }
  }
}

// ---------------- V transposes (fp32 [N][64] slices -> bf16 [C][N]) ----------------
__global__ __launch_bounds__(TB) void tr32_kernel(const float* __restrict__ v,
                                                  unsigned short* __restrict__ vt) {
  __shared__ float tile[256][33];
  const int t = threadIdx.x;
  const int bh = blockIdx.y, b = bh >> 1, h = bh & 1;
  const int r0 = blockIdx.x * 256;
  const float* src = v + ((size_t)b * 2048 + r0) * 64 + h * 32;
#pragma unroll
  for (int i = 0; i < 8; ++i) {
    int f4 = t + i * 256;            // 2048 float4 chunks
    int row = f4 >> 3, c4 = f4 & 7;
    float4 xv = *reinterpret_cast<const float4*>(src + (size_t)row * 64 + c4 * 4);
    tile[row][c4 * 4 + 0] = xv.x; tile[row][c4 * 4 + 1] = xv.y;
    tile[row][c4 * 4 + 2] = xv.z; tile[row][c4 * 4 + 3] = xv.w;
  }
  __syncthreads();
  unsigned short* dstb = vt + (size_t)bh * 32 * 2048 + r0;
#pragma unroll
  for (int i = 0; i < 4; ++i) {
    int ch = t + i * 256;            // 1024 ushort8 chunks: d 0..31, rb 0..31
    int d = ch >> 5, rb = ch & 31;
    us8 o;
#pragma unroll
    for (int e = 0; e < 8; ++e) o[e] = f2b(tile[rb * 8 + e][d]);
    *reinterpret_cast<us8*>(dstb + (size_t)d * 2048 + rb * 8) = o;
  }
}

__global__ __launch_bounds__(TB) void tr64_kernel(const float* __restrict__ v,
                                                  unsigned short* __restrict__ vt) {
  __shared__ float tile[128][65];
  const int t = threadIdx.x;
  const int b = blockIdx.y;
  const int r0 = blockIdx.x * 128;
  const float* src = v + ((size_t)b * 2048 + r0) * 64;
#pragma unroll
  for (int i = 0; i < 8; ++i) {
    int f4 = t + i * 256;            // 2048 float4 chunks
    int row = f4 >> 4, c4 = f4 & 15;
    float4 xv = *reinterpret_cast<const float4*>(src + (size_t)row * 64 + c4 * 4);
    tile[row][c4 * 4 + 0] = xv.x; tile[row][c4 * 4 + 1] = xv.y;
    tile[row][c4 * 4 + 2] = xv.z; tile[row][c4 * 4 + 3] = xv.w;
  }
  __syncthreads();
  unsigned short* dstb = vt + (size_t)b * 64 * 2048 + r0;
#pragma unroll
  for (int i = 0; i < 4; ++i) {
    int ch = t + i * 256;            // 1024 chunks: d 0..63, rb 0..15
    int d = ch >> 4, rb = ch & 15;
    us8 o;
#pragma unroll
    for (int e = 0; e < 8; ++e) o[e] = f2b(tile[rb * 8 + e][d]);
    *reinterpret_cast<us8*>(dstb + (size_t)d * 2048 + rb * 8) = o;
  }
}

// ---------------- edge bitmask ----------------
__global__ void zero_mask_kernel(unsigned int* __restrict__ mb) {
  mb[(size_t)blockIdx.x * TB + threadIdx.x] = 0u;
}
__global__ void scatter_kernel(const int* __restrict__ edge, int E,
                               unsigned int* __restrict__ mb) {
  int e = blockIdx.x * TB + threadIdx.x;
  if (e < E) {
    int r = edge[e];
    int c = edge[E + e];
    atomicOr(&mb[r * (N_ / 32) + (c >> 5)], 1u << (c & 31));
  }
}

// ---------------- DMHSA (MFMA): 16 rows/block, 4 waves x 512-col strips ----------------
__global__ __launch_bounds__(TB, 2) void dmhsa_kernel(
    const unsigned short* __restrict__ q16, const unsigned short* __restrict__ k16,
    const unsigned short* __restrict__ vt16,
    float* __restrict__ od, float* __restrict__ attn_out) {
  __shared__ __align__(16) char lds[16 * 4096];   // S/P bf16 [16][2048], swizzled
  __shared__ float redsum[4][16], redmax[4][16];
  __shared__ float rowmean[16], rowmax[16], rowrinv[16];

  const int t = threadIdx.x, w = t >> 6, lane = t & 63;
  const int g = lane >> 4, m = lane & 15;
  const int bh = blockIdx.y;
  const int row0 = blockIdx.x * 16;
  const size_t qkbase = (size_t)bh * 2048 * 32;

  // A-frag: Q rows (lane: row m, k = 8g..8g+7)
  bf16x8 aq = *reinterpret_cast<const bf16x8*>(q16 + qkbase + (size_t)(row0 + m) * 32 + 8 * g);

  // ---- phase 1: S = q@k^T (scale folded into q16), bf16 store + fp32 row stats ----
  float rs[4] = {0.f, 0.f, 0.f, 0.f};
  float rm[4] = {-1e30f, -1e30f, -1e30f, -1e30f};
  const int c0w = w * 512;
  for (int jt = 0; jt < 32; ++jt) {
    int c0 = c0w + jt * 16;
    bf16x8 bk = *reinterpret_cast<const bf16x8*>(k16 + qkbase + (size_t)(c0 + m) * 32 + 8 * g);
    f32x4 z = {0.f, 0.f, 0.f, 0.f};
    f32x4 acc = MFMA16(aq, bk, z);
#pragma unroll
    for (int r = 0; r < 4; ++r) {
      float v = acc[r];
      rs[r] += v; rm[r] = fmaxf(rm[r], v);
      int row = 4 * g + r;
      *reinterpret_cast<unsigned short*>(lds + swz(row * 4096 + (c0 + m) * 2)) = f2b(v);
    }
  }
#pragma unroll
  for (int off = 1; off < 16; off <<= 1) {
#pragma unroll
    for (int r = 0; r < 4; ++r) {
      rs[r] += __shfl_xor(rs[r], off, 64);
      rm[r] = fmaxf(rm[r], __shfl_xor(rm[r], off, 64));
    }
  }
  if (m == 0) {
#pragma unroll
    for (int r = 0; r < 4; ++r) { redsum[w][4 * g + r] = rs[r]; redmax[w][4 * g + r] = rm[r]; }
  }
  __syncthreads();
  if (t < 16) {
    float s = redsum[0][t] + redsum[1][t] + redsum[2][t] + redsum[3][t];
    float mx = fmaxf(fmaxf(redmax[0][t], redmax[1][t]), fmaxf(redmax[2][t], redmax[3][t]));
    rowmean[t] = s * (1.f / 2048.f);
    rowmax[t] = mx;
  }
  __syncthreads();

  // ---- phase 3a: mask+exp (P bf16 in-place) + denom; wave w owns rows 4w..4w+3 ----
#pragma unroll
  for (int rr = 0; rr < 4; ++rr) {
    int row = w * 4 + rr;
    float mean = rowmean[row], mx = rowmax[row];
    float part = 0.f;
#pragma unroll
    for (int kc = 0; kc < 4; ++kc) {
      us8* p = reinterpret_cast<us8*>(lds + swz(row * 4096 + lane * 16 + kc * 1024));
      us8 sv = *p;
      us8 pv;
#pragma unroll
      for (int e = 0; e < 8; ++e) {
        float s = b2f(sv[e]);
        float ev = (s >= mean) ? __expf(s - mx) : 0.f;
        part += ev;
        pv[e] = f2b(ev);
      }
      *p = pv;
    }
    part = wave_reduce_sum(part);
    if (lane == 0) rowrinv[row] = 1.f / part;
  }
  __syncthreads();

  // ---- phase 3b: attn = P * rinv (fp32, coalesced) ----
  {
    float* aout = attn_out + ((size_t)bh * 2048 + row0) * 2048;
#pragma unroll
    for (int rr = 0; rr < 4; ++rr) {
      int row = w * 4 + rr;
      float rinv = rowrinv[row];
#pragma unroll
      for (int kc = 0; kc < 4; ++kc) {
        us8 pv = *reinterpret_cast<const us8*>(lds + swz(row * 4096 + lane * 16 + kc * 1024));
        int col = lane * 8 + kc * 512;
        float4 o0, o1;
        o0.x = b2f(pv[0]) * rinv; o0.y = b2f(pv[1]) * rinv;
        o0.z = b2f(pv[2]) * rinv; o0.w = b2f(pv[3]) * rinv;
        o1.x = b2f(pv[4]) * rinv; o1.y = b2f(pv[5]) * rinv;
        o1.z = b2f(pv[6]) * rinv; o1.w = b2f(pv[7]) * rinv;
        *reinterpret_cast<float4*>(aout + (size_t)row * 2048 + col) = o0;
        *reinterpret_cast<float4*>(aout + (size_t)row * 2048 + col + 4) = o1;
      }
    }
  }

  // ---- phase 4: O = P @ V via MFMA over wave's j-strip; cross-wave reduce in LDS ----
  f32x4 oa0 = {0.f, 0.f, 0.f, 0.f}, oa1 = {0.f, 0.f, 0.f, 0.f};
  const unsigned short* vtb = vt16 + (size_t)bh * 32 * 2048;
  for (int jc = 0; jc < 16; ++jc) {
    int j0 = w * 512 + jc * 32;
    bf16x8 ap = *reinterpret_cast<const bf16x8*>(lds + swz(m * 4096 + (j0 + 8 * g) * 2));
    bf16x8 bv0 = *reinterpret_cast<const bf16x8*>(vtb + (size_t)m * 2048 + j0 + 8 * g);
    bf16x8 bv1 = *reinterpret_cast<const bf16x8*>(vtb + (size_t)(16 + m) * 2048 + j0 + 8 * g);
    oa0 = MFMA16(ap, bv0, oa0);
    oa1 = MFMA16(ap, bv1, oa1);
  }
  __syncthreads();                       // all P reads done -> alias obuf onto lds
  float* obuf = reinterpret_cast<float*>(lds);   // [4][16][32]
#pragma unroll
  for (int r = 0; r < 4; ++r) {
    obuf[(w * 16 + 4 * g + r) * 32 + m] = oa0[r];
    obuf[(w * 16 + 4 * g + r) * 32 + 16 + m] = oa1[r];
  }
  __syncthreads();
  {
    const int b = bh >> 1, h = bh & 1;
    int idx = t;
#pragma unroll
    for (int u = 0; u < 2; ++u, idx += 256) {
      int row = idx >> 5, d = idx & 31;
      float o = obuf[(0 * 16 + row) * 32 + d] + obuf[(1 * 16 + row) * 32 + d] +
                obuf[(2 * 16 + row) * 32 + d] + obuf[(3 * 16 + row) * 32 + d];
      od[((size_t)b * 2048 + row0 + row) * 64 + h * 32 + d] = o * rowrinv[row];
    }
  }
}

// ---------------- SSA (MFMA): 16 rows/block, edge-mask softmax ----------------
__global__ __launch_bounds__(TB, 2) void ssa_kernel(
    const unsigned short* __restrict__ q16, const unsigned short* __restrict__ k16,
    const unsigned short* __restrict__ vt16, const unsigned int* __restrict__ mb,
    float* __restrict__ osb) {
  __shared__ __align__(16) char lds[16 * 4096];
  __shared__ float rowrinv[16];

  const int t = threadIdx.x, w = t >> 6, lane = t & 63;
  const int g = lane >> 4, m = lane & 15;
  const int b = blockIdx.y;
  const int row0 = blockIdx.x * 16;
  const size_t base = (size_t)b * 2048 * 64;

  bf16x8 aq0 = *reinterpret_cast<const bf16x8*>(q16 + base + (size_t)(row0 + m) * 64 + 8 * g);
  bf16x8 aq1 = *reinterpret_cast<const bf16x8*>(q16 + base + (size_t)(row0 + m) * 64 + 32 + 8 * g);

  // ---- phase 1: raw scores bf16 (scale folded into q16s) ----
  const int c0w = w * 512;
  for (int jt = 0; jt < 32; ++jt) {
    int c0 = c0w + jt * 16;
    bf16x8 bk0 = *reinterpret_cast<const bf16x8*>(k16 + base + (size_t)(c0 + m) * 64 + 8 * g);
    bf16x8 bk1 = *reinterpret_cast<const bf16x8*>(k16 + base + (size_t)(c0 + m) * 64 + 32 + 8 * g);
    f32x4 z = {0.f, 0.f, 0.f, 0.f};
    f32x4 acc = MFMA16(aq0, bk0, z);
    acc = MFMA16(aq1, bk1, acc);
#pragma unroll
    for (int r = 0; r < 4; ++r) {
      int row = 4 * g + r;
      *reinterpret_cast<unsigned short*>(lds + swz(row * 4096 + (c0 + m) * 2)) = f2b(acc[r]);
    }
  }
  __syncthreads();

  // ---- phase 2/3: masked max, exp, denom, P bf16 in-place; wave w owns rows 4w..4w+3 ----
#pragma unroll
  for (int rr = 0; rr < 4; ++rr) {
    int row = w * 4 + rr;
    const unsigned char* mbb = reinterpret_cast<const unsigned char*>(mb) + (size_t)(row0 + row) * 256;
    float rmx = -1e30f;
#pragma unroll
    for (int kc = 0; kc < 4; ++kc) {
      us8 sv = *reinterpret_cast<const us8*>(lds + swz(row * 4096 + lane * 16 + kc * 1024));
      unsigned int mby = mbb[lane + kc * 64];
#pragma unroll
      for (int e = 0; e < 8; ++e) {
        float s = ((mby >> e) & 1u) ? b2f(sv[e]) : NEGV;
        rmx = fmaxf(rmx, s);
      }
    }
    rmx = wave_reduce_max(rmx);
    float part = 0.f;
#pragma unroll
    for (int kc = 0; kc < 4; ++kc) {
      us8* p = reinterpret_cast<us8*>(lds + swz(row * 4096 + lane * 16 + kc * 1024));
      us8 sv = *p;
      us8 pv;
#pragma unroll
      for (int e = 0; e < 8; ++e) {
        float s = ((mbb[lane + kc * 64] >> e) & 1u) ? b2f(sv[e]) : NEGV;
        float ev = __expf(s - rmx);     // all-masked row -> exp(0)=1 uniform (matches ref)
        part += ev;
        pv[e] = f2b(ev);
      }
      *p = pv;
    }
    part = wave_reduce_sum(part);
    if (lane == 0) rowrinv[row] = 1.f / part;
  }
  __syncthreads();

  // ---- phase 4: O = P @ V (64 dims = 4 blocks) ----
  f32x4 oa[4];
#pragma unroll
  for (int d = 0; d < 4; ++d) oa[d] = (f32x4){0.f, 0.f, 0.f, 0.f};
  const unsigned short* vtb = vt16 + (size_t)b * 64 * 2048;
  for (int jc = 0; jc < 16; ++jc) {
    int j0 = w * 512 + jc * 32;
    bf16x8 ap = *reinterpret_cast<const bf16x8*>(lds + swz(m * 4096 + (j0 + 8 * g) * 2));
#pragma unroll
    for (int db = 0; db < 4; ++db) {
      bf16x8 bv = *reinterpret_cast<const bf16x8*>(vtb + (size_t)(db * 16 + m) * 2048 + j0 + 8 * g);
      oa[db] = MFMA16(ap, bv, oa[db]);
    }
  }
  __syncthreads();
  float* obuf = reinterpret_cast<float*>(lds);   // [4][16][64] fp32 = 16KB
#pragma unroll
  for (int db = 0; db < 4; ++db)
#pragma unroll
    for (int r = 0; r < 4; ++r)
      obuf[(w * 16 + 4 * g + r) * 64 + db * 16 + m] = oa[db][r];
  __syncthreads();
  {
    int idx = t;
#pragma unroll
    for (int u = 0; u < 4; ++u, idx += 256) {
      int row = idx >> 6, d = idx & 63;
      float o = obuf[(0 * 16 + row) * 64 + d] + obuf[(1 * 16 + row) * 64 + d] +
                obuf[(2 * 16 + row) * 64 + d] + obuf[(3 * 16 + row) * 64 + d];
      osb[base + (size_t)(row0 + row) * 64 + d] = o * rowrinv[row];
    }
  }
}

// ---------------- residual + LN1 + MLP + LN2 ----------------
__global__ __launch_bounds__(TB) void epi_kernel(
    const float* __restrict__ x, const float* __restrict__ od,
    const float* __restrict__ osb,
    const float* __restrict__ g1, const float* __restrict__ bb1,
    const float* __restrict__ g2, const float* __restrict__ bb2,
    const float* __restrict__ w1, const float* __restrict__ bm1,
    const float* __restrict__ w2, const float* __restrict__ bm2,
    float* __restrict__ out) {
  __shared__ float hl[4][64];
  __shared__ float tl[4][128];
  const int t = threadIdx.x, wv = t >> 6, c = t & 63;
  const size_t row = (size_t)blockIdx.x * 4 + wv;
  const size_t base = row * 64 + c;
  float res = od[base] + osb[base] + x[base];
  float mean = wave_reduce_sum(res) * (1.f / 64.f);
  float dlt = res - mean;
  float var = wave_reduce_sum(dlt * dlt) * (1.f / 64.f);
  float hval = dlt * rsqrtf(var + LN_EPS) * g1[c] + bb1[c];
  hl[wv][c] = hval;
  __syncthreads();
  float t0 = bm1[2 * c], t1 = bm1[2 * c + 1];
#pragma unroll 16
  for (int cc = 0; cc < 64; ++cc) {
    float hv = hl[wv][cc];
    float2 wv2 = *reinterpret_cast<const float2*>(w1 + (size_t)cc * 128 + 2 * c);
    t0 += hv * wv2.x; t1 += hv * wv2.y;
  }
  *reinterpret_cast<float2*>(&tl[wv][2 * c]) = make_float2(t0, t1);
  __syncthreads();
  float mo = bm2[c];
#pragma unroll 8
  for (int j4 = 0; j4 < 32; ++j4) {
    float4 t4 = *reinterpret_cast<const float4*>(&tl[wv][j4 * 4]);
    mo += t4.x * w2[(size_t)(j4 * 4 + 0) * 64 + c];
    mo += t4.y * w2[(size_t)(j4 * 4 + 1) * 64 + c];
    mo += t4.z * w2[(size_t)(j4 * 4 + 2) * 64 + c];
    mo += t4.w * w2[(size_t)(j4 * 4 + 3) * 64 + c];
  }
  float y = mo + res;
  float mean2 = wave_reduce_sum(y) * (1.f / 64.f);
  float d2 = y - mean2;
  float var2 = wave_reduce_sum(d2 * d2) * (1.f / 64.f);
  out[base] = d2 * rsqrtf(var2 + LN_EPS) * g2[c] + bb2[c];
}

extern "C" void kernel_launch(void* const* d_in, const int* in_sizes, int n_in,
                              void* d_out, int out_size, void* d_ws, size_t ws_size,
                              hipStream_t stream) {
  const float* x    = (const float*)d_in[0];
  const int*   edge = (const int*)d_in[1];
  const float* wqd = (const float*)d_in[3];
  const float* wkd = (const float*)d_in[4];
  const float* wvd = (const float*)d_in[5];
  const float* bvd = (const float*)d_in[6];
  const float* wqs = (const float*)d_in[7];
  const float* wks = (const float*)d_in[8];
  const float* wvs = (const float*)d_in[9];
  const float* bvs = (const float*)d_in[10];
  const float* g1  = (const float*)d_in[11];
  const float* b1g = (const float*)d_in[12];
  const float* g2  = (const float*)d_in[13];
  const float* b2g = (const float*)d_in[14];
  const float* w1  = (const float*)d_in[15];
  const float* bm1 = (const float*)d_in[16];
  const float* w2  = (const float*)d_in[17];
  const float* bm2 = (const float*)d_in[18];
  const int E = in_sizes[1] / 2;

  float* out  = (float*)d_out;
  float* attn = out + SCH;                  // [B,H,N,N] fp32

  char* W = (char*)d_ws;
  float*          vd    = (float*)(W);                                 // 4MB
  float*          vsb   = (float*)(W + ((size_t)4  << 20));            // 4MB
  float*          od    = (float*)(W + ((size_t)8  << 20));            // 4MB
  float*          osb   = (float*)(W + ((size_t)12 << 20));            // 4MB
  unsigned short* q16d  = (unsigned short*)(W + ((size_t)16 << 20));   // 2MB
  unsigned short* k16d  = (unsigned short*)(W + ((size_t)18 << 20));   // 2MB
  unsigned short* q16s  = (unsigned short*)(W + ((size_t)20 << 20));   // 2MB
  unsigned short* k16s  = (unsigned short*)(W + ((size_t)22 << 20));   // 2MB
  unsigned short* vt16d = (unsigned short*)(W + ((size_t)24 << 20));   // 2MB
  unsigned short* vt16s = (unsigned short*)(W + ((size_t)26 << 20));   // 2MB
  unsigned int*   mb    = (unsigned int*)(W + ((size_t)28 << 20));     // 512KB

  proj_kernel<<<(B_ * N_) / 16, TB, 0, stream>>>(x, wqd, wkd, wvd, bvd, wqs, wks, wvs, bvs,
                                                 vd, vsb, q16d, k16d, q16s, k16s);
  tr32_kernel<<<dim3(8, 16), TB, 0, stream>>>(vd, vt16d);
  tr64_kernel<<<dim3(16, 8), TB, 0, stream>>>(vsb, vt16s);
  zero_mask_kernel<<<(N_ * N_ / 32) / TB, TB, 0, stream>>>(mb);
  scatter_kernel<<<(E + TB - 1) / TB, TB, 0, stream>>>(edge, E, mb);
  dmhsa_kernel<<<dim3(128, 16), TB, 0, stream>>>(q16d, k16d, vt16d, od, attn);
  ssa_kernel<<<dim3(128, 8), TB, 0, stream>>>(q16s, k16s, vt16s, mb, osb);
  epi_kernel<<<(B_ * N_) / 4, TB, 0, stream>>>(x, od, osb, g1, b1g, g2, b2g, w1, bm1, w2, bm2, out);
}

// Round 10
// 540.895 us; speedup vs baseline: 2.0320x; 1.0324x over previous
//
#include <hip/hip_runtime.h>
#include <hip/hip_bf16.h>

#define TB 256
#define TBA 512

constexpr int B_ = 8, N_ = 2048, H_ = 2;
constexpr float SCALE = 0.125f;      // C**-0.5, exact power of two
constexpr float NEGV = -1e10f;
constexpr float LN_EPS = 1e-5f;
constexpr size_t SCH = (size_t)B_ * N_ * 64;   // 1M elements per [B,N,C]

typedef __attribute__((ext_vector_type(8))) short bf16x8;
typedef __attribute__((ext_vector_type(4))) float f32x4;
typedef __attribute__((ext_vector_type(8))) unsigned short us8;
typedef __attribute__((ext_vector_type(4))) unsigned short us4;

#define MFMA16(A, B, C) __builtin_amdgcn_mfma_f32_16x16x32_bf16((A), (B), (C), 0, 0, 0)

__device__ __forceinline__ unsigned short f2b(float f) {
  __hip_bfloat16 h = __float2bfloat16(f);
  return *reinterpret_cast<unsigned short*>(&h);
}
__device__ __forceinline__ float b2f(unsigned short u) {
  union { unsigned int i; float f; } v; v.i = ((unsigned int)u) << 16; return v.f;
}
// S-tile LDS swizzle: rows are 4096B, XOR row&7 into the 16B-block index (G4 fix)
__device__ __forceinline__ int swz(int off) { return off ^ (((off >> 12) & 7) << 4); }

__device__ __forceinline__ float wave_reduce_sum(float v) {
#pragma unroll
  for (int off = 32; off >= 1; off >>= 1) v += __shfl_xor(v, off, 64);
  return v;
}
__device__ __forceinline__ float wave_reduce_max(float v) {
#pragma unroll
  for (int off = 32; off >= 1; off >>= 1) v = fmaxf(v, __shfl_xor(v, off, 64));
  return v;
}

// ---------------- projections ----------------
// outputs: q16d,k16d [B*H][N][32] bf16 (q pre-scaled), vd fp32 [B][N][64] (+bias)
//          q16s,k16s [B][N][64] bf16 (q pre-scaled), vsb fp32 [B][N][64] (+bias)
__global__ __launch_bounds__(TB) void proj_kernel(
    const float* __restrict__ x,
    const float* __restrict__ wqd, const float* __restrict__ wkd,
    const float* __restrict__ wvd, const float* __restrict__ bvd,
    const float* __restrict__ wqs, const float* __restrict__ wks,
    const float* __restrict__ wvs, const float* __restrict__ bvs,
    float* __restrict__ vd, float* __restrict__ vsb,
    unsigned short* __restrict__ q16d, unsigned short* __restrict__ k16d,
    unsigned short* __restrict__ q16s, unsigned short* __restrict__ k16s) {
  const int t = threadIdx.x;
  const int row = blockIdx.x * 16 + (t >> 4);
  const int cg = t & 15;
  const int b = row >> 11, n = row & 2047;
  float xr[64];
  const float4* xp = reinterpret_cast<const float4*>(x + (size_t)row * 64);
#pragma unroll
  for (int i = 0; i < 16; ++i) {
    float4 v = xp[i];
    xr[4 * i] = v.x; xr[4 * i + 1] = v.y; xr[4 * i + 2] = v.z; xr[4 * i + 3] = v.w;
  }
  const float* W[6] = {wqd, wkd, wvd, wqs, wks, wvs};
#pragma unroll
  for (int m = 0; m < 6; ++m) {
    float4 acc = make_float4(0.f, 0.f, 0.f, 0.f);
    if (m == 2) acc = reinterpret_cast<const float4*>(bvd)[cg];
    if (m == 5) acc = reinterpret_cast<const float4*>(bvs)[cg];
    const float4* wp = reinterpret_cast<const float4*>(W[m]) + cg;
#pragma unroll
    for (int c = 0; c < 64; ++c) {
      float4 w4 = wp[(size_t)c * 16];
      float s = xr[c];
      acc.x += s * w4.x; acc.y += s * w4.y; acc.z += s * w4.z; acc.w += s * w4.w;
    }
    if (m == 2) {
      reinterpret_cast<float4*>(vd + (size_t)row * 64)[cg] = acc;
    } else if (m == 5) {
      reinterpret_cast<float4*>(vsb + (size_t)row * 64)[cg] = acc;
    } else {
      float sc = (m == 0 || m == 3) ? SCALE : 1.f;
      us4 o; o.x = f2b(acc.x * sc); o.y = f2b(acc.y * sc);
      o.z = f2b(acc.z * sc); o.w = f2b(acc.w * sc);
      if (m == 0 || m == 1) {
        unsigned short* dst = (m == 0) ? q16d : k16d;
        size_t idx = ((size_t)(b * 2 + (cg >> 3)) * 2048 + n) * 32 + (cg & 7) * 4;
        *reinterpret_cast<us4*>(dst + idx) = o;
      } else {
        unsigned short* dst = (m == 3) ? q16s : k16s;
        *reinterpret_cast<us4*>(dst + (size_t)row * 64 + cg * 4) = o;
      }
    }
  }
}

// ---------------- V transposes (fp32 [N][64] slices -> bf16 [C][N]) ----------------
__global__ __launch_bounds__(TB) void tr32_kernel(const float* __restrict__ v,
                                                  unsigned short* __restrict__ vt) {
  __shared__ float tile[256][33];
  const int t = threadIdx.x;
  const int bh = blockIdx.y, b = bh >> 1, h = bh & 1;
  const int r0 = blockIdx.x * 256;
  const float* src = v + ((size_t)b * 2048 + r0) * 64 + h * 32;
#pragma unroll
  for (int i = 0; i < 8; ++i) {
    int f4 = t + i * 256;            // 2048 float4 chunks
    int row = f4 >> 3, c4 = f4 & 7;
    float4 xv = *reinterpret_cast<const float4*>(src + (size_t)row * 64 + c4 * 4);
    tile[row][c4 * 4 + 0] = xv.x; tile[row][c4 * 4 + 1] = xv.y;
    tile[row][c4 * 4 + 2] = xv.z; tile[row][c4 * 4 + 3] = xv.w;
  }
  __syncthreads();
  unsigned short* dstb = vt + (size_t)bh * 32 * 2048 + r0;
#pragma unroll
  for (int i = 0; i < 4; ++i) {
    int ch = t + i * 256;            // 1024 ushort8 chunks: d 0..31, rb 0..31
    int d = ch >> 5, rb = ch & 31;
    us8 o;
#pragma unroll
    for (int e = 0; e < 8; ++e) o[e] = f2b(tile[rb * 8 + e][d]);
    *reinterpret_cast<us8*>(dstb + (size_t)d * 2048 + rb * 8) = o;
  }
}

__global__ __launch_bounds__(TB) void tr64_kernel(const float* __restrict__ v,
                                                  unsigned short* __restrict__ vt) {
  __shared__ float tile[128][65];
  const int t = threadIdx.x;
  const int b = blockIdx.y;
  const int r0 = blockIdx.x * 128;
  const float* src = v + ((size_t)b * 2048 + r0) * 64;
#pragma unroll
  for (int i = 0; i < 8; ++i) {
    int f4 = t + i * 256;            // 2048 float4 chunks
    int row = f4 >> 4, c4 = f4 & 15;
    float4 xv = *reinterpret_cast<const float4*>(src + (size_t)row * 64 + c4 * 4);
    tile[row][c4 * 4 + 0] = xv.x; tile[row][c4 * 4 + 1] = xv.y;
    tile[row][c4 * 4 + 2] = xv.z; tile[row][c4 * 4 + 3] = xv.w;
  }
  __syncthreads();
  unsigned short* dstb = vt + (size_t)b * 64 * 2048 + r0;
#pragma unroll
  for (int i = 0; i < 4; ++i) {
    int ch = t + i * 256;            // 1024 chunks: d 0..63, rb 0..15
    int d = ch >> 4, rb = ch & 15;
    us8 o;
#pragma unroll
    for (int e = 0; e < 8; ++e) o[e] = f2b(tile[rb * 8 + e][d]);
    *reinterpret_cast<us8*>(dstb + (size_t)d * 2048 + rb * 8) = o;
  }
}

// ---------------- edge bitmask ----------------
__global__ void zero_mask_kernel(unsigned int* __restrict__ mb) {
  mb[(size_t)blockIdx.x * TB + threadIdx.x] = 0u;
}
__global__ void scatter_kernel(const int* __restrict__ edge, int E,
                               unsigned int* __restrict__ mb) {
  int e = blockIdx.x * TB + threadIdx.x;
  if (e < E) {
    int r = edge[e];
    int c = edge[E + e];
    atomicOr(&mb[r * (N_ / 32) + (c >> 5)], 1u << (c & 31));
  }
}

// ---------------- DMHSA (MFMA): 16 rows/block, 8 waves x 256-col strips ----------------
__global__ __launch_bounds__(TBA, 4) void dmhsa_kernel(
    const unsigned short* __restrict__ q16, const unsigned short* __restrict__ k16,
    const unsigned short* __restrict__ vt16,
    float* __restrict__ od, float* __restrict__ attn_out) {
  __shared__ __align__(16) char lds[16 * 4096];   // S/P bf16 [16][2048], swizzled
  __shared__ float redsum[8][16], redmax[8][16];
  __shared__ float rowmean[16], rowmax[16], rowrinv[16];

  const int t = threadIdx.x, w = t >> 6, lane = t & 63;
  const int g = lane >> 4, m = lane & 15;
  const int bh = blockIdx.y;
  const int row0 = blockIdx.x * 16;
  const size_t qkbase = (size_t)bh * 2048 * 32;

  // A-frag: Q rows (lane: row m, k = 8g..8g+7)
  bf16x8 aq = *reinterpret_cast<const bf16x8*>(q16 + qkbase + (size_t)(row0 + m) * 32 + 8 * g);

  // ---- phase 1: S = q@k^T (scale folded into q16), bf16 store + fp32 row stats ----
  float rs[4] = {0.f, 0.f, 0.f, 0.f};
  float rm[4] = {-1e30f, -1e30f, -1e30f, -1e30f};
  const int c0w = w * 256;
  for (int jt = 0; jt < 16; ++jt) {
    int c0 = c0w + jt * 16;
    bf16x8 bk = *reinterpret_cast<const bf16x8*>(k16 + qkbase + (size_t)(c0 + m) * 32 + 8 * g);
    f32x4 z = {0.f, 0.f, 0.f, 0.f};
    f32x4 acc = MFMA16(aq, bk, z);
#pragma unroll
    for (int r = 0; r < 4; ++r) {
      float v = acc[r];
      rs[r] += v; rm[r] = fmaxf(rm[r], v);
      int row = 4 * g + r;
      *reinterpret_cast<unsigned short*>(lds + swz(row * 4096 + (c0 + m) * 2)) = f2b(v);
    }
  }
#pragma unroll
  for (int off = 1; off < 16; off <<= 1) {
#pragma unroll
    for (int r = 0; r < 4; ++r) {
      rs[r] += __shfl_xor(rs[r], off, 64);
      rm[r] = fmaxf(rm[r], __shfl_xor(rm[r], off, 64));
    }
  }
  if (m == 0) {
#pragma unroll
    for (int r = 0; r < 4; ++r) { redsum[w][4 * g + r] = rs[r]; redmax[w][4 * g + r] = rm[r]; }
  }
  __syncthreads();
  if (t < 16) {
    float s = 0.f, mx = -1e30f;
#pragma unroll
    for (int ww = 0; ww < 8; ++ww) {
      s += redsum[ww][t];
      mx = fmaxf(mx, redmax[ww][t]);
    }
    rowmean[t] = s * (1.f / 2048.f);
    rowmax[t] = mx;
  }
  __syncthreads();

  // ---- phase 3a: mask+exp (P bf16 in-place) + denom; wave w owns rows 2w..2w+1 ----
#pragma unroll
  for (int rr = 0; rr < 2; ++rr) {
    int row = w * 2 + rr;
    float mean = rowmean[row], mx = rowmax[row];
    float part = 0.f;
#pragma unroll
    for (int kc = 0; kc < 4; ++kc) {
      us8* p = reinterpret_cast<us8*>(lds + swz(row * 4096 + lane * 16 + kc * 1024));
      us8 sv = *p;
      us8 pv;
#pragma unroll
      for (int e = 0; e < 8; ++e) {
        float s = b2f(sv[e]);
        float ev = (s >= mean) ? __expf(s - mx) : 0.f;
        part += ev;
        pv[e] = f2b(ev);
      }
      *p = pv;
    }
    part = wave_reduce_sum(part);
    if (lane == 0) rowrinv[row] = 1.f / part;
  }
  __syncthreads();

  // ---- phase 3b: attn = P * rinv (fp32, coalesced) ----
  {
    float* aout = attn_out + ((size_t)bh * 2048 + row0) * 2048;
#pragma unroll
    for (int rr = 0; rr < 2; ++rr) {
      int row = w * 2 + rr;
      float rinv = rowrinv[row];
#pragma unroll
      for (int kc = 0; kc < 4; ++kc) {
        us8 pv = *reinterpret_cast<const us8*>(lds + swz(row * 4096 + lane * 16 + kc * 1024));
        int col = lane * 8 + kc * 512;
        float4 o0, o1;
        o0.x = b2f(pv[0]) * rinv; o0.y = b2f(pv[1]) * rinv;
        o0.z = b2f(pv[2]) * rinv; o0.w = b2f(pv[3]) * rinv;
        o1.x = b2f(pv[4]) * rinv; o1.y = b2f(pv[5]) * rinv;
        o1.z = b2f(pv[6]) * rinv; o1.w = b2f(pv[7]) * rinv;
        *reinterpret_cast<float4*>(aout + (size_t)row * 2048 + col) = o0;
        *reinterpret_cast<float4*>(aout + (size_t)row * 2048 + col + 4) = o1;
      }
    }
  }

  // ---- phase 4: O = P @ V via MFMA over wave's j-strip; cross-wave reduce in LDS ----
  f32x4 oa0 = {0.f, 0.f, 0.f, 0.f}, oa1 = {0.f, 0.f, 0.f, 0.f};
  const unsigned short* vtb = vt16 + (size_t)bh * 32 * 2048;
  for (int jc = 0; jc < 8; ++jc) {
    int j0 = w * 256 + jc * 32;
    bf16x8 ap = *reinterpret_cast<const bf16x8*>(lds + swz(m * 4096 + (j0 + 8 * g) * 2));
    bf16x8 bv0 = *reinterpret_cast<const bf16x8*>(vtb + (size_t)m * 2048 + j0 + 8 * g);
    bf16x8 bv1 = *reinterpret_cast<const bf16x8*>(vtb + (size_t)(16 + m) * 2048 + j0 + 8 * g);
    oa0 = MFMA16(ap, bv0, oa0);
    oa1 = MFMA16(ap, bv1, oa1);
  }
  __syncthreads();                       // all P reads done -> alias obuf onto lds
  float* obuf = reinterpret_cast<float*>(lds);   // [8][16][32] = 16KB
#pragma unroll
  for (int r = 0; r < 4; ++r) {
    obuf[(w * 16 + 4 * g + r) * 32 + m] = oa0[r];
    obuf[(w * 16 + 4 * g + r) * 32 + 16 + m] = oa1[r];
  }
  __syncthreads();
  {
    const int b = bh >> 1, h = bh & 1;
    int row = t >> 5, d = t & 31;        // 512 threads = 16 rows x 32 dims
    float o = 0.f;
#pragma unroll
    for (int s = 0; s < 8; ++s) o += obuf[(s * 16 + row) * 32 + d];
    od[((size_t)b * 2048 + row0 + row) * 64 + h * 32 + d] = o * rowrinv[row];
  }
}

// ---------------- SSA (MFMA): 16 rows/block, 8 waves, edge-mask softmax ----------------
__global__ __launch_bounds__(TBA, 4) void ssa_kernel(
    const unsigned short* __restrict__ q16, const unsigned short* __restrict__ k16,
    const unsigned short* __restrict__ vt16, const unsigned int* __restrict__ mb,
    float* __restrict__ osb) {
  __shared__ __align__(16) char lds[16 * 4096];
  __shared__ float rowrinv[16];

  const int t = threadIdx.x, w = t >> 6, lane = t & 63;
  const int g = lane >> 4, m = lane & 15;
  const int b = blockIdx.y;
  const int row0 = blockIdx.x * 16;
  const size_t base = (size_t)b * 2048 * 64;

  bf16x8 aq0 = *reinterpret_cast<const bf16x8*>(q16 + base + (size_t)(row0 + m) * 64 + 8 * g);
  bf16x8 aq1 = *reinterpret_cast<const bf16x8*>(q16 + base + (size_t)(row0 + m) * 64 + 32 + 8 * g);

  // ---- phase 1: raw scores bf16 (scale folded into q16s) ----
  const int c0w = w * 256;
  for (int jt = 0; jt < 16; ++jt) {
    int c0 = c0w + jt * 16;
    bf16x8 bk0 = *reinterpret_cast<const bf16x8*>(k16 + base + (size_t)(c0 + m) * 64 + 8 * g);
    bf16x8 bk1 = *reinterpret_cast<const bf16x8*>(k16 + base + (size_t)(c0 + m) * 64 + 32 + 8 * g);
    f32x4 z = {0.f, 0.f, 0.f, 0.f};
    f32x4 acc = MFMA16(aq0, bk0, z);
    acc = MFMA16(aq1, bk1, acc);
#pragma unroll
    for (int r = 0; r < 4; ++r) {
      int row = 4 * g + r;
      *reinterpret_cast<unsigned short*>(lds + swz(row * 4096 + (c0 + m) * 2)) = f2b(acc[r]);
    }
  }
  __syncthreads();

  // ---- phase 2/3: masked max, exp, denom, P bf16 in-place; wave w owns rows 2w..2w+1 ----
#pragma unroll
  for (int rr = 0; rr < 2; ++rr) {
    int row = w * 2 + rr;
    const unsigned char* mbb = reinterpret_cast<const unsigned char*>(mb) + (size_t)(row0 + row) * 256;
    float rmx = -1e30f;
#pragma unroll
    for (int kc = 0; kc < 4; ++kc) {
      us8 sv = *reinterpret_cast<const us8*>(lds + swz(row * 4096 + lane * 16 + kc * 1024));
      unsigned int mby = mbb[lane + kc * 64];
#pragma unroll
      for (int e = 0; e < 8; ++e) {
        float s = ((mby >> e) & 1u) ? b2f(sv[e]) : NEGV;
        rmx = fmaxf(rmx, s);
      }
    }
    rmx = wave_reduce_max(rmx);
    float part = 0.f;
#pragma unroll
    for (int kc = 0; kc < 4; ++kc) {
      us8* p = reinterpret_cast<us8*>(lds + swz(row * 4096 + lane * 16 + kc * 1024));
      us8 sv = *p;
      us8 pv;
      unsigned int mby = mbb[lane + kc * 64];
#pragma unroll
      for (int e = 0; e < 8; ++e) {
        float s = ((mby >> e) & 1u) ? b2f(sv[e]) : NEGV;
        float ev = __expf(s - rmx);     // all-masked row -> exp(0)=1 uniform (matches ref)
        part += ev;
        pv[e] = f2b(ev);
      }
      *p = pv;
    }
    part = wave_reduce_sum(part);
    if (lane == 0) rowrinv[row] = 1.f / part;
  }
  __syncthreads();

  // ---- phase 4: O = P @ V (64 dims = 4 blocks) ----
  f32x4 oa[4];
#pragma unroll
  for (int d = 0; d < 4; ++d) oa[d] = (f32x4){0.f, 0.f, 0.f, 0.f};
  const unsigned short* vtb = vt16 + (size_t)b * 64 * 2048;
  for (int jc = 0; jc < 8; ++jc) {
    int j0 = w * 256 + jc * 32;
    bf16x8 ap = *reinterpret_cast<const bf16x8*>(lds + swz(m * 4096 + (j0 + 8 * g) * 2));
#pragma unroll
    for (int db = 0; db < 4; ++db) {
      bf16x8 bv = *reinterpret_cast<const bf16x8*>(vtb + (size_t)(db * 16 + m) * 2048 + j0 + 8 * g);
      oa[db] = MFMA16(ap, bv, oa[db]);
    }
  }
  __syncthreads();
  float* obuf = reinterpret_cast<float*>(lds);   // [8][16][64] fp32 = 32KB
#pragma unroll
  for (int db = 0; db < 4; ++db)
#pragma unroll
    for (int r = 0; r < 4; ++r)
      obuf[(w * 16 + 4 * g + r) * 64 + db * 16 + m] = oa[db][r];
  __syncthreads();
  {
#pragma unroll
    for (int u = 0; u < 2; ++u) {
      int idx = t + u * TBA;
      int row = idx >> 6, d = idx & 63;  // 1024 = 16 rows x 64 dims
      float o = 0.f;
#pragma unroll
      for (int s = 0; s < 8; ++s) o += obuf[(s * 16 + row) * 64 + d];
      osb[base + (size_t)(row0 + row) * 64 + d] = o * rowrinv[row];
    }
  }
}

// ---------------- residual + LN1 + MLP + LN2 ----------------
__global__ __launch_bounds__(TB) void epi_kernel(
    const float* __restrict__ x, const float* __restrict__ od,
    const float* __restrict__ osb,
    const float* __restrict__ g1, const float* __restrict__ bb1,
    const float* __restrict__ g2, const float* __restrict__ bb2,
    const float* __restrict__ w1, const float* __restrict__ bm1,
    const float* __restrict__ w2, const float* __restrict__ bm2,
    float* __restrict__ out) {
  __shared__ float hl[4][64];
  __shared__ float tl[4][128];
  const int t = threadIdx.x, wv = t >> 6, c = t & 63;
  const size_t row = (size_t)blockIdx.x * 4 + wv;
  const size_t base = row * 64 + c;
  float res = od[base] + osb[base] + x[base];
  float mean = wave_reduce_sum(res) * (1.f / 64.f);
  float dlt = res - mean;
  float var = wave_reduce_sum(dlt * dlt) * (1.f / 64.f);
  float hval = dlt * rsqrtf(var + LN_EPS) * g1[c] + bb1[c];
  hl[wv][c] = hval;
  __syncthreads();
  float t0 = bm1[2 * c], t1 = bm1[2 * c + 1];
#pragma unroll 16
  for (int cc = 0; cc < 64; ++cc) {
    float hv = hl[wv][cc];
    float2 wv2 = *reinterpret_cast<const float2*>(w1 + (size_t)cc * 128 + 2 * c);
    t0 += hv * wv2.x; t1 += hv * wv2.y;
  }
  *reinterpret_cast<float2*>(&tl[wv][2 * c]) = make_float2(t0, t1);
  __syncthreads();
  float mo = bm2[c];
#pragma unroll 8
  for (int j4 = 0; j4 < 32; ++j4) {
    float4 t4 = *reinterpret_cast<const float4*>(&tl[wv][j4 * 4]);
    mo += t4.x * w2[(size_t)(j4 * 4 + 0) * 64 + c];
    mo += t4.y * w2[(size_t)(j4 * 4 + 1) * 64 + c];
    mo += t4.z * w2[(size_t)(j4 * 4 + 2) * 64 + c];
    mo += t4.w * w2[(size_t)(j4 * 4 + 3) * 64 + c];
  }
  float y = mo + res;
  float mean2 = wave_reduce_sum(y) * (1.f / 64.f);
  float d2 = y - mean2;
  float var2 = wave_reduce_sum(d2 * d2) * (1.f / 64.f);
  out[base] = d2 * rsqrtf(var2 + LN_EPS) * g2[c] + bb2[c];
}

extern "C" void kernel_launch(void* const* d_in, const int* in_sizes, int n_in,
                              void* d_out, int out_size, void* d_ws, size_t ws_size,
                              hipStream_t stream) {
  const float* x    = (const float*)d_in[0];
  const int*   edge = (const int*)d_in[1];
  const float* wqd = (const float*)d_in[3];
  const float* wkd = (const float*)d_in[4];
  const float* wvd = (const float*)d_in[5];
  const float* bvd = (const float*)d_in[6];
  const float* wqs = (const float*)d_in[7];
  const float* wks = (const float*)d_in[8];
  const float* wvs = (const float*)d_in[9];
  const float* bvs = (const float*)d_in[10];
  const float* g1  = (const float*)d_in[11];
  const float* b1g = (const float*)d_in[12];
  const float* g2  = (const float*)d_in[13];
  const float* b2g = (const float*)d_in[14];
  const float* w1  = (const float*)d_in[15];
  const float* bm1 = (const float*)d_in[16];
  const float* w2  = (const float*)d_in[17];
  const float* bm2 = (const float*)d_in[18];
  const int E = in_sizes[1] / 2;

  float* out  = (float*)d_out;
  float* attn = out + SCH;                  // [B,H,N,N] fp32

  char* W = (char*)d_ws;
  float*          vd    = (float*)(W);                                 // 4MB
  float*          vsb   = (float*)(W + ((size_t)4  << 20));            // 4MB
  float*          od    = (float*)(W + ((size_t)8  << 20));            // 4MB
  float*          osb   = (float*)(W + ((size_t)12 << 20));            // 4MB
  unsigned short* q16d  = (unsigned short*)(W + ((size_t)16 << 20));   // 2MB
  unsigned short* k16d  = (unsigned short*)(W + ((size_t)18 << 20));   // 2MB
  unsigned short* q16s  = (unsigned short*)(W + ((size_t)20 << 20));   // 2MB
  unsigned short* k16s  = (unsigned short*)(W + ((size_t)22 << 20));   // 2MB
  unsigned short* vt16d = (unsigned short*)(W + ((size_t)24 << 20));   // 2MB
  unsigned short* vt16s = (unsigned short*)(W + ((size_t)26 << 20));   // 2MB
  unsigned int*   mb    = (unsigned int*)(W + ((size_t)28 << 20));     // 512KB

  proj_kernel<<<(B_ * N_) / 16, TB, 0, stream>>>(x, wqd, wkd, wvd, bvd, wqs, wks, wvs, bvs,
                                                 vd, vsb, q16d, k16d, q16s, k16s);
  tr32_kernel<<<dim3(8, 16), TB, 0, stream>>>(vd, vt16d);
  tr64_kernel<<<dim3(16, 8), TB, 0, stream>>>(vsb, vt16s);
  zero_mask_kernel<<<(N_ * N_ / 32) / TB, TB, 0, stream>>>(mb);
  scatter_kernel<<<(E + TB - 1) / TB, TB, 0, stream>>>(edge, E, mb);
  dmhsa_kernel<<<dim3(128, 16), TBA, 0, stream>>>(q16d, k16d, vt16d, od, attn);
  ssa_kernel<<<dim3(128, 8), TBA, 0, stream>>>(q16s, k16s, vt16s, mb, osb);
  epi_kernel<<<(B_ * N_) / 4, TB, 0, stream>>>(x, od, osb, g1, b1g, g2, b2g, w1, bm1, w2, bm2, out);
}